// Round 1
// baseline (1966.311 us; speedup 1.0000x reference)
//
#include <hip/hip_runtime.h>

typedef __bf16 bf16_t;
typedef __bf16 bf16x8 __attribute__((ext_vector_type(8)));
typedef __bf16 bf16x4 __attribute__((ext_vector_type(4)));
typedef float floatx4 __attribute__((ext_vector_type(4)));

#define D_MODEL 4096
#define SEQ 2048
#define BATCH 2
#define NH 32
#define HD 128
#define AL 10
#define MROWS (BATCH * SEQ)   // 4096
#define N_QKV (3 * D_MODEL)   // 12288

static __device__ __forceinline__ void gload_lds16(const void* g, void* l) {
  __builtin_amdgcn_global_load_lds((const __attribute__((address_space(1))) void*)g,
                                   (__attribute__((address_space(3))) void*)l, 16, 0, 0);
}

// ---------------- fp32 -> bf16 bulk convert ----------------
__global__ void convert_bf16_kernel(const float* __restrict__ src, bf16_t* __restrict__ dst) {
  size_t i = ((size_t)blockIdx.x * 256 + threadIdx.x) * 4;
  float4 v = *(const float4*)(src + i);
  bf16x4 o;
  o[0] = (bf16_t)v.x; o[1] = (bf16_t)v.y; o[2] = (bf16_t)v.z; o[3] = (bf16_t)v.w;
  *(bf16x4*)(dst + i) = o;
}

// ---------------- transpose (D,D) fp32 -> (D,D) bf16 (dst[n][k] = src[k][n]) ----------------
__global__ void transpose_conv_kernel(const float* __restrict__ src, bf16_t* __restrict__ dst) {
  __shared__ float tile[32][33];
  const int tx = threadIdx.x & 31;
  const int ty = threadIdx.x >> 5;
  const int c0 = blockIdx.x * 32;  // source col
  const int r0 = blockIdx.y * 32;  // source row
#pragma unroll
  for (int i = 0; i < 4; i++) {
    int r = ty + i * 8;
    tile[r][tx] = src[(size_t)(r0 + r) * D_MODEL + c0 + tx];
  }
  __syncthreads();
#pragma unroll
  for (int i = 0; i < 4; i++) {
    int r = ty + i * 8;
    dst[(size_t)(c0 + r) * D_MODEL + r0 + tx] = (bf16_t)tile[tx][r];
  }
}

// ---------------- transpose V block of QKV (bf16) -> VT[b][d][s] ----------------
// VT[(b*D + c)][s] = QKV[(b*S + s)][2*D + c]
__global__ void vt_kernel(const bf16_t* __restrict__ QKV, bf16_t* __restrict__ VT) {
  __shared__ bf16_t tile[32][33];
  const int tx = threadIdx.x & 31;
  const int ty = threadIdx.x >> 5;
  const int s0 = blockIdx.x * 32;
  const int c0 = blockIdx.y * 32;
  const int b = blockIdx.z;
  const bf16_t* src = QKV + (size_t)b * SEQ * N_QKV + 2 * D_MODEL;
#pragma unroll
  for (int i = 0; i < 4; i++) {
    int r = ty + i * 8;
    tile[r][tx] = src[(size_t)(s0 + r) * N_QKV + c0 + tx];
  }
  __syncthreads();
  bf16_t* dst = VT + (size_t)b * D_MODEL * SEQ;
#pragma unroll
  for (int i = 0; i < 4; i++) {
    int r = ty + i * 8;
    dst[(size_t)(c0 + r) * SEQ + s0 + tx] = tile[tx][r];
  }
}

// ---------------- 128x128 tile bf16 MFMA GEMM, B given transposed (Bt[n][k]) ----------------
template <typename OT>
__global__ __launch_bounds__(256) void gemm_bt_kernel(const bf16_t* __restrict__ A,
                                                      const bf16_t* __restrict__ Bt,
                                                      OT* __restrict__ C, int M, int N, int K) {
  __shared__ __align__(16) bf16_t As[128 * 32];
  __shared__ __align__(16) bf16_t Bs[128 * 32];
  const int tid = threadIdx.x;
  const int lane = tid & 63;
  const int wave = tid >> 6;
  const int quad = lane >> 4;
  const int l16 = lane & 15;
  const int m0 = blockIdx.y * 128;
  const int n0 = blockIdx.x * 128;
  const int wm = (wave >> 1) * 64;
  const int wn = (wave & 1) * 64;
  floatx4 acc[4][4] = {};
  for (int k0 = 0; k0 < K; k0 += 32) {
#pragma unroll
    for (int r = 0; r < 2; r++) {
      int c = r * 256 + tid;  // 512 chunks of 16B per tile; row = c>>2, k-quarter = c&3
      gload_lds16(A + (size_t)(m0 + (c >> 2)) * K + k0 + (c & 3) * 8, As + c * 8);
      gload_lds16(Bt + (size_t)(n0 + (c >> 2)) * K + k0 + (c & 3) * 8, Bs + c * 8);
    }
    __syncthreads();
    bf16x8 af[4], bfv[4];
#pragma unroll
    for (int i = 0; i < 4; i++)
      af[i] = *(const bf16x8*)(As + (wm + i * 16 + l16) * 32 + quad * 8);
#pragma unroll
    for (int j = 0; j < 4; j++)
      bfv[j] = *(const bf16x8*)(Bs + (wn + j * 16 + l16) * 32 + quad * 8);
#pragma unroll
    for (int i = 0; i < 4; i++)
#pragma unroll
      for (int j = 0; j < 4; j++)
        acc[i][j] = __builtin_amdgcn_mfma_f32_16x16x32_bf16(af[i], bfv[j], acc[i][j], 0, 0, 0);
    __syncthreads();
  }
#pragma unroll
  for (int i = 0; i < 4; i++)
#pragma unroll
    for (int j = 0; j < 4; j++) {
      int m = m0 + wm + i * 16 + quad * 4;  // + r
      int n = n0 + wn + j * 16 + l16;
#pragma unroll
      for (int r = 0; r < 4; r++) C[(size_t)(m + r) * N + n] = (OT)acc[i][j][r];
    }
}

// ---------------- RoPE in place on Q,K halves of QKV (interleaved pairs) ----------------
__global__ void rope_kernel(bf16_t* __restrict__ QKV, const float* __restrict__ cosb,
                            const float* __restrict__ sinb) {
  int idx = blockIdx.x * 256 + threadIdx.x;  // (row, half, h, i)
  int i = idx & 63;
  int h = (idx >> 6) & 31;
  int half = (idx >> 11) & 1;
  int row = idx >> 12;
  int s = row & (SEQ - 1);
  size_t off = (size_t)row * N_QKV + half * D_MODEL + h * HD + 2 * i;
  float c = cosb[s * 64 + i], sn = sinb[s * 64 + i];
  float x0 = (float)QKV[off], x1 = (float)QKV[off + 1];
  QKV[off] = (bf16_t)(x0 * c - x1 * sn);
  QKV[off + 1] = (bf16_t)(x0 * sn + x1 * c);
}

__global__ void zero_kernel(float* __restrict__ p, int n) {
  int i = blockIdx.x * 256 + threadIdx.x;
  if (i < n) p[i] = 0.f;
}

// ---------------- adapter GEMMs: ak = adapter@wk, av = adapter@wv (fp32) ----------------
__global__ __launch_bounds__(256) void adapter_gemm_kernel(const float* __restrict__ adp,
                                                           const float* __restrict__ wk,
                                                           const float* __restrict__ wv,
                                                           float* __restrict__ ak,
                                                           float* __restrict__ av) {
  const float* W = blockIdx.y ? wv : wk;
  float* out = blockIdx.y ? av : ak;
  const int n = blockIdx.x * 256 + threadIdx.x;
  const int kb = blockIdx.z * 512;
  __shared__ float a_s[AL][512];
  for (int t = threadIdx.x; t < AL * 512; t += 256)
    a_s[t / 512][t % 512] = adp[(t / 512) * D_MODEL + kb + (t % 512)];
  __syncthreads();
  float accv[AL] = {};
  for (int kk = 0; kk < 512; kk++) {
    float w = W[(size_t)(kb + kk) * D_MODEL + n];
#pragma unroll
    for (int a = 0; a < AL; a++) accv[a] += a_s[a][kk] * w;
  }
#pragma unroll
  for (int a = 0; a < AL; a++) atomicAdd(&out[a * D_MODEL + n], accv[a]);
}

// ---------------- flash attention + fused gated adapter attention ----------------
// 4 waves/block (256 threads). All waves share one q-tile index (same loop counts, so the
// block-wide __syncthreads P-transpose is uniform); each wave handles a DIFFERENT head.
// V is consumed from pre-transposed VT[b][d][s] -> one bf16x8 load per dt (was 64 scalar
// gathers per k-tile). q-tiles processed longest-first (LPT) to shrink the causal tail.
// MFMA layouts (HW-verified, guide §3): A: m=lane&15,k=quad*8+j; C/D: col=lane&15,row=quad*4+reg.
__global__ __launch_bounds__(256) void flash_kernel(const bf16_t* __restrict__ QKV,
                                                    const bf16_t* __restrict__ VT,
                                                    const float* __restrict__ akp,
                                                    const float* __restrict__ avp,
                                                    const float* __restrict__ gatep,
                                                    bf16_t* __restrict__ Out) {
  const int lane = threadIdx.x & 63;
  const int wave = threadIdx.x >> 6;
  const int quad = lane >> 4;
  const int l16 = lane & 15;
  const int q0 = (gridDim.x - 1 - blockIdx.x) * 32;  // LPT: longest blocks first
  const int bh = blockIdx.y * 4 + wave;
  const int b = bh >> 5;
  const int h = bh & 31;
  const size_t base = (size_t)b * SEQ * N_QKV;
  const int hoff = h * HD;
  const float scale = 0.08838834764831845f;  // 1/sqrt(128)
  __shared__ __align__(16) bf16_t Pl[4][2][16][32];

  const bf16_t* vtb = VT + (size_t)(b * D_MODEL + hoff) * SEQ;

  // Q fragments (A-operand), kept in registers for the whole block
  bf16x8 qa[2][4];
#pragma unroll
  for (int mt = 0; mt < 2; mt++) {
    const bf16_t* qrow = QKV + base + (size_t)(q0 + mt * 16 + l16) * N_QKV + hoff + quad * 8;
#pragma unroll
    for (int c = 0; c < 4; c++) qa[mt][c] = *(const bf16x8*)(qrow + c * 32);
  }
  floatx4 acc[2][8] = {};
  float Mx[2][4], Ls[2][4];
#pragma unroll
  for (int mt = 0; mt < 2; mt++)
#pragma unroll
    for (int r = 0; r < 4; r++) { Mx[mt][r] = -1e30f; Ls[mt][r] = 0.f; }

  for (int j0 = 0; j0 <= q0; j0 += 32) {
    // K fragments (B-operand): n=key(lane&15), k=d(quad*8+j) -> contiguous 16B per lane
    bf16x8 kf[2][4];
#pragma unroll
    for (int nt = 0; nt < 2; nt++) {
      const bf16_t* krow =
          QKV + base + (size_t)(j0 + nt * 16 + l16) * N_QKV + D_MODEL + hoff + quad * 8;
#pragma unroll
      for (int c = 0; c < 4; c++) kf[nt][c] = *(const bf16x8*)(krow + c * 32);
    }
    // V fragments (B-operand for PV): n=d(lane&15 within dtile), k=key(quad*8+jj)
    // VT row (d) is contiguous in s -> single 16B load per dt
    bf16x8 vf[8];
#pragma unroll
    for (int dt = 0; dt < 8; dt++)
      vf[dt] = *(const bf16x8*)(vtb + (size_t)(dt * 16 + l16) * SEQ + j0 + quad * 8);

    const bool diag = (j0 == q0);
#pragma unroll
    for (int mt = 0; mt < 2; mt++) {
      floatx4 s0 = {}, s1 = {};
#pragma unroll
      for (int c = 0; c < 4; c++) {
        s0 = __builtin_amdgcn_mfma_f32_16x16x32_bf16(qa[mt][c], kf[0][c], s0, 0, 0, 0);
        s1 = __builtin_amdgcn_mfma_f32_16x16x32_bf16(qa[mt][c], kf[1][c], s1, 0, 0, 0);
      }
      const int rowg = q0 + mt * 16 + quad * 4;  // + r
      float alpha[4];
#pragma unroll
      for (int r = 0; r < 4; r++) {
        float v0 = s0[r] * scale;
        float v1 = s1[r] * scale;
        if (diag) {
          if (j0 + l16 > rowg + r) v0 = -1e30f;
          if (j0 + 16 + l16 > rowg + r) v1 = -1e30f;
        }
        float mx = fmaxf(v0, v1);
#pragma unroll
        for (int off = 8; off; off >>= 1) mx = fmaxf(mx, __shfl_xor(mx, off, 64));
        float nm = fmaxf(Mx[mt][r], mx);
        alpha[r] = __expf(Mx[mt][r] - nm);
        Mx[mt][r] = nm;
        float p0 = __expf(v0 - nm);
        float p1 = __expf(v1 - nm);
        float rs = p0 + p1;
#pragma unroll
        for (int off = 8; off; off >>= 1) rs += __shfl_xor(rs, off, 64);
        Ls[mt][r] = Ls[mt][r] * alpha[r] + rs;
        Pl[wave][mt][quad * 4 + r][l16] = (bf16_t)p0;
        Pl[wave][mt][quad * 4 + r][l16 + 16] = (bf16_t)p1;
      }
#pragma unroll
      for (int dt = 0; dt < 8; dt++)
#pragma unroll
        for (int r = 0; r < 4; r++) acc[mt][dt][r] *= alpha[r];
    }
    __syncthreads();  // P writes -> P reads (C-layout -> A-layout transpose via LDS)
#pragma unroll
    for (int mt = 0; mt < 2; mt++) {
      bf16x8 pf = *(const bf16x8*)(&Pl[wave][mt][l16][quad * 8]);
#pragma unroll
      for (int dt = 0; dt < 8; dt++)
        acc[mt][dt] = __builtin_amdgcn_mfma_f32_16x16x32_bf16(pf, vf[dt], acc[mt][dt], 0, 0, 0);
    }
    __syncthreads();  // P reads done before next iteration overwrites
  }

  // ---- gated adapter attention (separate softmax over 10 tokens, no mask) ----
  const float gate = gatep[h];
#pragma unroll
  for (int mt = 0; mt < 2; mt++) {
    floatx4 sa = {};
#pragma unroll
    for (int c = 0; c < 4; c++) {
      bf16x8 bak;
#pragma unroll
      for (int jj = 0; jj < 8; jj++) {
        float v = (l16 < AL) ? akp[(size_t)l16 * D_MODEL + hoff + c * 32 + quad * 8 + jj] : 0.f;
        bak[jj] = (bf16_t)v;
      }
      sa = __builtin_amdgcn_mfma_f32_16x16x32_bf16(qa[mt][c], bak, sa, 0, 0, 0);
    }
#pragma unroll
    for (int r = 0; r < 4; r++) {
      float v = (l16 < AL) ? sa[r] * scale : -1e30f;
      float mx = v;
#pragma unroll
      for (int off = 8; off; off >>= 1) mx = fmaxf(mx, __shfl_xor(mx, off, 64));
      float p = __expf(v - mx);
      float rs = p;
#pragma unroll
      for (int off = 8; off; off >>= 1) rs += __shfl_xor(rs, off, 64);
      float pa = p / rs;
      Pl[wave][mt][quad * 4 + r][l16] = (l16 < AL) ? (bf16_t)pa : (bf16_t)0.f;
      Pl[wave][mt][quad * 4 + r][l16 + 16] = (bf16_t)0.f;
    }
  }
  __syncthreads();
  bf16x8 avf[8];
#pragma unroll
  for (int jj = 0; jj < 8; jj++) {
    int j = quad * 8 + jj;
#pragma unroll
    for (int dt = 0; dt < 8; dt++) {
      float v = (j < AL) ? avp[(size_t)j * D_MODEL + hoff + dt * 16 + l16] : 0.f;
      avf[dt][jj] = (bf16_t)v;
    }
  }
#pragma unroll
  for (int mt = 0; mt < 2; mt++) {
    bf16x8 pf = *(const bf16x8*)(&Pl[wave][mt][l16][quad * 8]);
#pragma unroll
    for (int dt = 0; dt < 8; dt++) {
      floatx4 z = {};
      floatx4 oa = __builtin_amdgcn_mfma_f32_16x16x32_bf16(pf, avf[dt], z, 0, 0, 0);
#pragma unroll
      for (int r = 0; r < 4; r++) {
        int m = q0 + mt * 16 + quad * 4 + r;
        float val = acc[mt][dt][r] / Ls[mt][r] + gate * oa[r];
        Out[(size_t)(b * SEQ + m) * D_MODEL + hoff + dt * 16 + l16] = (bf16_t)val;
      }
    }
  }
}

extern "C" void kernel_launch(void* const* d_in, const int* in_sizes, int n_in, void* d_out,
                              int out_size, void* d_ws, size_t ws_size, hipStream_t stream) {
  const float* x = (const float*)d_in[0];
  const float* cosb = (const float*)d_in[1];
  const float* sinb = (const float*)d_in[2];
  // d_in[3] = mask (causal, implemented analytically)
  const float* wq = (const float*)d_in[4];
  const float* wk = (const float*)d_in[5];
  const float* wv = (const float*)d_in[6];
  const float* wo = (const float*)d_in[7];
  const float* gate = (const float*)d_in[8];
  const float* adp = (const float*)d_in[9];
  // d_in[10] = random_init (always 0 -> non-concat branch)
  float* out = (float*)d_out;

  char* ws = (char*)d_ws;
  const size_t DD = (size_t)D_MODEL * D_MODEL;
  bf16_t* Wt = (bf16_t*)(ws);                  // (3D, K) stacked wq^T,wk^T,wv^T
  bf16_t* Wot = (bf16_t*)(ws + 3 * DD * 2);    // wo^T
  bf16_t* Xb = (bf16_t*)(ws + 4 * DD * 2);     // x as bf16 (M,K); reused as VT after QKV GEMM
  bf16_t* QKV = (bf16_t*)(ws + 5 * DD * 2);    // (M, 3D)
  bf16_t* Att = (bf16_t*)(ws + 8 * DD * 2);    // (M, D)
  float* akb = (float*)(ws + 9 * DD * 2);      // (AL, D)
  float* avb = akb + AL * D_MODEL;             // (AL, D)
  bf16_t* VT = Xb;                             // (B*D, S) bf16 = DD*2 bytes, Xb is dead by then

  convert_bf16_kernel<<<MROWS * D_MODEL / 1024, 256, 0, stream>>>(x, Xb);
  transpose_conv_kernel<<<dim3(128, 128), 256, 0, stream>>>(wq, Wt);
  transpose_conv_kernel<<<dim3(128, 128), 256, 0, stream>>>(wk, Wt + DD);
  transpose_conv_kernel<<<dim3(128, 128), 256, 0, stream>>>(wv, Wt + 2 * DD);
  transpose_conv_kernel<<<dim3(128, 128), 256, 0, stream>>>(wo, Wot);
  gemm_bt_kernel<bf16_t><<<dim3(N_QKV / 128, MROWS / 128), 256, 0, stream>>>(
      Xb, Wt, QKV, MROWS, N_QKV, D_MODEL);
  rope_kernel<<<(MROWS * 4096) / 256, 256, 0, stream>>>(QKV, cosb, sinb);
  vt_kernel<<<dim3(SEQ / 32, D_MODEL / 32, BATCH), 256, 0, stream>>>(QKV, VT);
  zero_kernel<<<(2 * AL * D_MODEL + 255) / 256, 256, 0, stream>>>(akb, 2 * AL * D_MODEL);
  adapter_gemm_kernel<<<dim3(D_MODEL / 256, 2, 8), 256, 0, stream>>>(adp, wk, wv, akb, avb);
  flash_kernel<<<dim3(SEQ / 32, (BATCH * NH) / 4), 256, 0, stream>>>(QKV, VT, akb, avb, gate, Att);
  gemm_bt_kernel<float><<<dim3(D_MODEL / 128, MROWS / 128), 256, 0, stream>>>(
      Att, Wot, out, MROWS, D_MODEL, D_MODEL);
}

// Round 3
// 1602.051 us; speedup vs baseline: 1.2274x; 1.2274x over previous
//
#include <hip/hip_runtime.h>

typedef __bf16 bf16_t;
typedef __bf16 bf16x8 __attribute__((ext_vector_type(8)));
typedef __bf16 bf16x4 __attribute__((ext_vector_type(4)));
typedef float floatx4 __attribute__((ext_vector_type(4)));

#define D_MODEL 4096
#define SEQ 2048
#define BATCH 2
#define NH 32
#define HD 128
#define AL 10
#define MROWS (BATCH * SEQ)   // 4096
#define N_QKV (3 * D_MODEL)   // 12288

static __device__ __forceinline__ void gload_lds16(const void* g, void* l) {
  __builtin_amdgcn_global_load_lds((const __attribute__((address_space(1))) void*)g,
                                   (__attribute__((address_space(3))) void*)l, 16, 0, 0);
}

// max across the 16-lane DPP row via fused v_max + row_ror (VALU latency, no LDS pipe)
#define DPP_MAX_STEP(v, ctrl)                                                             \
  v = fmaxf(v, __int_as_float(__builtin_amdgcn_update_dpp(                                \
                 __float_as_int(v), __float_as_int(v), ctrl, 0xF, 0xF, false)))
static __device__ __forceinline__ float rowmax16(float v) {
  DPP_MAX_STEP(v, 0x128);  // row_ror:8
  DPP_MAX_STEP(v, 0x124);  // row_ror:4
  DPP_MAX_STEP(v, 0x122);  // row_ror:2
  DPP_MAX_STEP(v, 0x121);  // row_ror:1
  return v;
}

// ---------------- fp32 -> bf16 bulk convert ----------------
__global__ void convert_bf16_kernel(const float* __restrict__ src, bf16_t* __restrict__ dst) {
  size_t i = ((size_t)blockIdx.x * 256 + threadIdx.x) * 4;
  float4 v = *(const float4*)(src + i);
  bf16x4 o;
  o[0] = (bf16_t)v.x; o[1] = (bf16_t)v.y; o[2] = (bf16_t)v.z; o[3] = (bf16_t)v.w;
  *(bf16x4*)(dst + i) = o;
}

// ---------------- transpose (D,D) fp32 -> (D,D) bf16 (dst[n][k] = src[k][n]) ----------------
__global__ void transpose_conv_kernel(const float* __restrict__ src, bf16_t* __restrict__ dst) {
  __shared__ float tile[32][33];
  const int tx = threadIdx.x & 31;
  const int ty = threadIdx.x >> 5;
  const int c0 = blockIdx.x * 32;  // source col
  const int r0 = blockIdx.y * 32;  // source row
#pragma unroll
  for (int i = 0; i < 4; i++) {
    int r = ty + i * 8;
    tile[r][tx] = src[(size_t)(r0 + r) * D_MODEL + c0 + tx];
  }
  __syncthreads();
#pragma unroll
  for (int i = 0; i < 4; i++) {
    int r = ty + i * 8;
    dst[(size_t)(c0 + r) * D_MODEL + r0 + tx] = (bf16_t)tile[tx][r];
  }
}

// ---------------- transpose V block of QKV (bf16) -> VT[b][d][s] ----------------
__global__ void vt_kernel(const bf16_t* __restrict__ QKV, bf16_t* __restrict__ VT) {
  __shared__ bf16_t tile[32][33];
  const int tx = threadIdx.x & 31;
  const int ty = threadIdx.x >> 5;
  const int s0 = blockIdx.x * 32;
  const int c0 = blockIdx.y * 32;
  const int b = blockIdx.z;
  const bf16_t* src = QKV + (size_t)b * SEQ * N_QKV + 2 * D_MODEL;
#pragma unroll
  for (int i = 0; i < 4; i++) {
    int r = ty + i * 8;
    tile[r][tx] = src[(size_t)(s0 + r) * N_QKV + c0 + tx];
  }
  __syncthreads();
  bf16_t* dst = VT + (size_t)b * D_MODEL * SEQ;
#pragma unroll
  for (int i = 0; i < 4; i++) {
    int r = ty + i * 8;
    dst[(size_t)(c0 + r) * SEQ + s0 + tx] = tile[tx][r];
  }
}

// ---------------- 128x128 tile bf16 MFMA GEMM, B given transposed (Bt[n][k]) ----------------
template <typename OT>
__global__ __launch_bounds__(256) void gemm_bt_kernel(const bf16_t* __restrict__ A,
                                                      const bf16_t* __restrict__ Bt,
                                                      OT* __restrict__ C, int M, int N, int K) {
  __shared__ __align__(16) bf16_t As[128 * 32];
  __shared__ __align__(16) bf16_t Bs[128 * 32];
  const int tid = threadIdx.x;
  const int lane = tid & 63;
  const int wave = tid >> 6;
  const int quad = lane >> 4;
  const int l16 = lane & 15;
  const int m0 = blockIdx.y * 128;
  const int n0 = blockIdx.x * 128;
  const int wm = (wave >> 1) * 64;
  const int wn = (wave & 1) * 64;
  floatx4 acc[4][4] = {};
  for (int k0 = 0; k0 < K; k0 += 32) {
#pragma unroll
    for (int r = 0; r < 2; r++) {
      int c = r * 256 + tid;  // 512 chunks of 16B per tile; row = c>>2, k-quarter = c&3
      gload_lds16(A + (size_t)(m0 + (c >> 2)) * K + k0 + (c & 3) * 8, As + c * 8);
      gload_lds16(Bt + (size_t)(n0 + (c >> 2)) * K + k0 + (c & 3) * 8, Bs + c * 8);
    }
    __syncthreads();
    bf16x8 af[4], bfv[4];
#pragma unroll
    for (int i = 0; i < 4; i++)
      af[i] = *(const bf16x8*)(As + (wm + i * 16 + l16) * 32 + quad * 8);
#pragma unroll
    for (int j = 0; j < 4; j++)
      bfv[j] = *(const bf16x8*)(Bs + (wn + j * 16 + l16) * 32 + quad * 8);
#pragma unroll
    for (int i = 0; i < 4; i++)
#pragma unroll
      for (int j = 0; j < 4; j++)
        acc[i][j] = __builtin_amdgcn_mfma_f32_16x16x32_bf16(af[i], bfv[j], acc[i][j], 0, 0, 0);
    __syncthreads();
  }
#pragma unroll
  for (int i = 0; i < 4; i++)
#pragma unroll
    for (int j = 0; j < 4; j++) {
      int m = m0 + wm + i * 16 + quad * 4;  // + r
      int n = n0 + wn + j * 16 + l16;
#pragma unroll
      for (int r = 0; r < 4; r++) C[(size_t)(m + r) * N + n] = (OT)acc[i][j][r];
    }
}

// ---------------- RoPE in place on Q,K halves of QKV (interleaved pairs) ----------------
__global__ void rope_kernel(bf16_t* __restrict__ QKV, const float* __restrict__ cosb,
                            const float* __restrict__ sinb) {
  int idx = blockIdx.x * 256 + threadIdx.x;  // (row, half, h, i)
  int i = idx & 63;
  int h = (idx >> 6) & 31;
  int half = (idx >> 11) & 1;
  int row = idx >> 12;
  int s = row & (SEQ - 1);
  size_t off = (size_t)row * N_QKV + half * D_MODEL + h * HD + 2 * i;
  float c = cosb[s * 64 + i], sn = sinb[s * 64 + i];
  float x0 = (float)QKV[off], x1 = (float)QKV[off + 1];
  QKV[off] = (bf16_t)(x0 * c - x1 * sn);
  QKV[off + 1] = (bf16_t)(x0 * sn + x1 * c);
}

__global__ void zero_kernel(float* __restrict__ p, int n) {
  int i = blockIdx.x * 256 + threadIdx.x;
  if (i < n) p[i] = 0.f;
}

// ---------------- adapter GEMMs: ak = adapter@wk, av = adapter@wv (fp32) ----------------
__global__ __launch_bounds__(256) void adapter_gemm_kernel(const float* __restrict__ adp,
                                                           const float* __restrict__ wk,
                                                           const float* __restrict__ wv,
                                                           float* __restrict__ ak,
                                                           float* __restrict__ av) {
  const float* W = blockIdx.y ? wv : wk;
  float* out = blockIdx.y ? av : ak;
  const int n = blockIdx.x * 256 + threadIdx.x;
  const int kb = blockIdx.z * 512;
  __shared__ float a_s[AL][512];
  for (int t = threadIdx.x; t < AL * 512; t += 256)
    a_s[t / 512][t % 512] = adp[(t / 512) * D_MODEL + kb + (t % 512)];
  __syncthreads();
  float accv[AL] = {};
  for (int kk = 0; kk < 512; kk++) {
    float w = W[(size_t)(kb + kk) * D_MODEL + n];
#pragma unroll
    for (int a = 0; a < AL; a++) accv[a] += a_s[a][kk] * w;
  }
#pragma unroll
  for (int a = 0; a < AL; a++) atomicAdd(&out[a * D_MODEL + n], accv[a]);
}

// ---------------- flash attention + fused gated adapter attention ----------------
// 4 waves/block; each wave a different head, all sharing one q-tile (uniform loop counts ->
// block barriers valid). Softmax cross-lane work minimized:
//   - row-max: 4 fused DPP row_ror v_max ops (VALU) instead of ds-swizzle shfl chains
//   - row-sum: one mfma(P, ones) per mt -> row-sums land exactly on Ls[mt][r] rows
// Grid = (head-groups, q-tiles reversed): x fastest => longest q-tiles dispatch first (LPT).
// MFMA layouts (HW-verified, guide §3): A: m=lane&15,k=quad*8+j; C/D: col=lane&15,row=quad*4+reg.
__global__ __launch_bounds__(256) void flash_kernel(const bf16_t* __restrict__ QKV,
                                                    const bf16_t* __restrict__ VT,
                                                    const float* __restrict__ akp,
                                                    const float* __restrict__ avp,
                                                    const float* __restrict__ gatep,
                                                    bf16_t* __restrict__ Out) {
  const int lane = threadIdx.x & 63;
  const int wave = threadIdx.x >> 6;
  const int quad = lane >> 4;
  const int l16 = lane & 15;
  const int q0 = (gridDim.y - 1 - blockIdx.y) * 32;  // LPT: longest tiles dispatch first
  const int bh = blockIdx.x * 4 + wave;
  const int b = bh >> 5;
  const int h = bh & 31;
  const size_t base = (size_t)b * SEQ * N_QKV;
  const int hoff = h * HD;
  const float scale = 0.08838834764831845f;  // 1/sqrt(128)
  __shared__ __align__(16) bf16_t Pl[4][2][16][32];

  const bf16_t* vtb = VT + (size_t)(b * D_MODEL + hoff) * SEQ;

  bf16x8 onesf;
#pragma unroll
  for (int j = 0; j < 8; j++) onesf[j] = (bf16_t)1.0f;

  // Q fragments (A-operand), kept in registers for the whole block
  bf16x8 qa[2][4];
#pragma unroll
  for (int mt = 0; mt < 2; mt++) {
    const bf16_t* qrow = QKV + base + (size_t)(q0 + mt * 16 + l16) * N_QKV + hoff + quad * 8;
#pragma unroll
    for (int c = 0; c < 4; c++) qa[mt][c] = *(const bf16x8*)(qrow + c * 32);
  }
  floatx4 acc[2][8] = {};
  float Mx[2][4], Ls[2][4];
#pragma unroll
  for (int mt = 0; mt < 2; mt++)
#pragma unroll
    for (int r = 0; r < 4; r++) { Mx[mt][r] = -1e30f; Ls[mt][r] = 0.f; }

  for (int j0 = 0; j0 <= q0; j0 += 32) {
    // K fragments (B-operand): n=key(lane&15), k=d(quad*8+j) -> contiguous 16B per lane
    bf16x8 kf[2][4];
#pragma unroll
    for (int nt = 0; nt < 2; nt++) {
      const bf16_t* krow =
          QKV + base + (size_t)(j0 + nt * 16 + l16) * N_QKV + D_MODEL + hoff + quad * 8;
#pragma unroll
      for (int c = 0; c < 4; c++) kf[nt][c] = *(const bf16x8*)(krow + c * 32);
    }
    // V fragments from VT[b][d][s]: one contiguous 16B load per dt
    bf16x8 vf[8];
#pragma unroll
    for (int dt = 0; dt < 8; dt++)
      vf[dt] = *(const bf16x8*)(vtb + (size_t)(dt * 16 + l16) * SEQ + j0 + quad * 8);

    const bool diag = (j0 == q0);
#pragma unroll
    for (int mt = 0; mt < 2; mt++) {
      floatx4 s0 = {}, s1 = {};
#pragma unroll
      for (int c = 0; c < 4; c++) {
        s0 = __builtin_amdgcn_mfma_f32_16x16x32_bf16(qa[mt][c], kf[0][c], s0, 0, 0, 0);
        s1 = __builtin_amdgcn_mfma_f32_16x16x32_bf16(qa[mt][c], kf[1][c], s1, 0, 0, 0);
      }
      const int rowg = q0 + mt * 16 + quad * 4;  // + r
#pragma unroll
      for (int r = 0; r < 4; r++) {
        float v0 = s0[r] * scale;
        float v1 = s1[r] * scale;
        if (diag) {
          if (j0 + l16 > rowg + r) v0 = -1e30f;
          if (j0 + 16 + l16 > rowg + r) v1 = -1e30f;
        }
        float mx = rowmax16(fmaxf(v0, v1));  // DPP reduce over the 16-lane row
        float nm = fmaxf(Mx[mt][r], mx);
        float alpha = __expf(Mx[mt][r] - nm);
        Mx[mt][r] = nm;
        float p0 = __expf(v0 - nm);
        float p1 = __expf(v1 - nm);
        Ls[mt][r] *= alpha;  // sum added after P readback via mfma(P, ones)
        Pl[wave][mt][quad * 4 + r][l16] = (bf16_t)p0;
        Pl[wave][mt][quad * 4 + r][l16 + 16] = (bf16_t)p1;
#pragma unroll
        for (int dt = 0; dt < 8; dt++) acc[mt][dt][r] *= alpha;
      }
    }
    __syncthreads();  // P writes -> P reads (C-layout -> A-layout transpose via LDS)
#pragma unroll
    for (int mt = 0; mt < 2; mt++) {
      bf16x8 pf = *(const bf16x8*)(&Pl[wave][mt][l16][quad * 8]);
      floatx4 lz = {};
      lz = __builtin_amdgcn_mfma_f32_16x16x32_bf16(pf, onesf, lz, 0, 0, 0);
#pragma unroll
      for (int dt = 0; dt < 8; dt++)
        acc[mt][dt] = __builtin_amdgcn_mfma_f32_16x16x32_bf16(pf, vf[dt], acc[mt][dt], 0, 0, 0);
#pragma unroll
      for (int r = 0; r < 4; r++) Ls[mt][r] += lz[r];  // row-sum lands on row quad*4+r
    }
    __syncthreads();  // P reads done before next iteration overwrites
  }

  // ---- gated adapter attention (separate softmax over 10 tokens, no mask) ----
  const float gate = gatep[h];
#pragma unroll
  for (int mt = 0; mt < 2; mt++) {
    floatx4 sa = {};
#pragma unroll
    for (int c = 0; c < 4; c++) {
      bf16x8 bak;
#pragma unroll
      for (int jj = 0; jj < 8; jj++) {
        float v = (l16 < AL) ? akp[(size_t)l16 * D_MODEL + hoff + c * 32 + quad * 8 + jj] : 0.f;
        bak[jj] = (bf16_t)v;
      }
      sa = __builtin_amdgcn_mfma_f32_16x16x32_bf16(qa[mt][c], bak, sa, 0, 0, 0);
    }
#pragma unroll
    for (int r = 0; r < 4; r++) {
      float v = (l16 < AL) ? sa[r] * scale : -1e30f;
      float mx = rowmax16(v);
      float p = __expf(v - mx);
      float rs = p;
#pragma unroll
      for (int off = 8; off; off >>= 1) rs += __shfl_xor(rs, off, 64);
      float pa = p / rs;
      Pl[wave][mt][quad * 4 + r][l16] = (l16 < AL) ? (bf16_t)pa : (bf16_t)0.f;
      Pl[wave][mt][quad * 4 + r][l16 + 16] = (bf16_t)0.f;
    }
  }
  __syncthreads();
  bf16x8 avf[8];
#pragma unroll
  for (int jj = 0; jj < 8; jj++) {
    int j = quad * 8 + jj;
#pragma unroll
    for (int dt = 0; dt < 8; dt++) {
      float v = (j < AL) ? avp[(size_t)j * D_MODEL + hoff + dt * 16 + l16] : 0.f;
      avf[dt][jj] = (bf16_t)v;
    }
  }
#pragma unroll
  for (int mt = 0; mt < 2; mt++) {
    bf16x8 pf = *(const bf16x8*)(&Pl[wave][mt][l16][quad * 8]);
#pragma unroll
    for (int dt = 0; dt < 8; dt++) {
      floatx4 z = {};
      floatx4 oa = __builtin_amdgcn_mfma_f32_16x16x32_bf16(pf, avf[dt], z, 0, 0, 0);
#pragma unroll
      for (int r = 0; r < 4; r++) {
        int m = q0 + mt * 16 + quad * 4 + r;
        float val = acc[mt][dt][r] / Ls[mt][r] + gate * oa[r];
        Out[(size_t)(b * SEQ + m) * D_MODEL + hoff + dt * 16 + l16] = (bf16_t)val;
      }
    }
  }
}

extern "C" void kernel_launch(void* const* d_in, const int* in_sizes, int n_in, void* d_out,
                              int out_size, void* d_ws, size_t ws_size, hipStream_t stream) {
  const float* x = (const float*)d_in[0];
  const float* cosb = (const float*)d_in[1];
  const float* sinb = (const float*)d_in[2];
  // d_in[3] = mask (causal, implemented analytically)
  const float* wq = (const float*)d_in[4];
  const float* wk = (const float*)d_in[5];
  const float* wv = (const float*)d_in[6];
  const float* wo = (const float*)d_in[7];
  const float* gate = (const float*)d_in[8];
  const float* adp = (const float*)d_in[9];
  // d_in[10] = random_init (always 0 -> non-concat branch)
  float* out = (float*)d_out;

  char* ws = (char*)d_ws;
  const size_t DD = (size_t)D_MODEL * D_MODEL;
  bf16_t* Wt = (bf16_t*)(ws);                  // (3D, K) stacked wq^T,wk^T,wv^T
  bf16_t* Wot = (bf16_t*)(ws + 3 * DD * 2);    // wo^T
  bf16_t* Xb = (bf16_t*)(ws + 4 * DD * 2);     // x as bf16 (M,K); reused as VT after QKV GEMM
  bf16_t* QKV = (bf16_t*)(ws + 5 * DD * 2);    // (M, 3D)
  bf16_t* Att = (bf16_t*)(ws + 8 * DD * 2);    // (M, D)
  float* akb = (float*)(ws + 9 * DD * 2);      // (AL, D)
  float* avb = akb + AL * D_MODEL;             // (AL, D)
  bf16_t* VT = Xb;                             // (B*D, S) bf16 = DD*2 bytes, Xb dead by then

  convert_bf16_kernel<<<MROWS * D_MODEL / 1024, 256, 0, stream>>>(x, Xb);
  transpose_conv_kernel<<<dim3(128, 128), 256, 0, stream>>>(wq, Wt);
  transpose_conv_kernel<<<dim3(128, 128), 256, 0, stream>>>(wk, Wt + DD);
  transpose_conv_kernel<<<dim3(128, 128), 256, 0, stream>>>(wv, Wt + 2 * DD);
  transpose_conv_kernel<<<dim3(128, 128), 256, 0, stream>>>(wo, Wot);
  gemm_bt_kernel<bf16_t><<<dim3(N_QKV / 128, MROWS / 128), 256, 0, stream>>>(
      Xb, Wt, QKV, MROWS, N_QKV, D_MODEL);
  rope_kernel<<<(MROWS * 4096) / 256, 256, 0, stream>>>(QKV, cosb, sinb);
  vt_kernel<<<dim3(SEQ / 32, D_MODEL / 32, BATCH), 256, 0, stream>>>(QKV, VT);
  zero_kernel<<<(2 * AL * D_MODEL + 255) / 256, 256, 0, stream>>>(akb, 2 * AL * D_MODEL);
  adapter_gemm_kernel<<<dim3(D_MODEL / 256, 2, 8), 256, 0, stream>>>(adp, wk, wv, akb, avb);
  flash_kernel<<<dim3((BATCH * NH) / 4, SEQ / 32), 256, 0, stream>>>(QKV, VT, akb, avb, gate,
                                                                     Att);
  gemm_bt_kernel<float><<<dim3(D_MODEL / 128, MROWS / 128), 256, 0, stream>>>(
      Att, Wot, out, MROWS, D_MODEL, D_MODEL);
}

// Round 4
// 1447.866 us; speedup vs baseline: 1.3581x; 1.1065x over previous
//
#include <hip/hip_runtime.h>

typedef __bf16 bf16_t;
typedef __bf16 bf16x8 __attribute__((ext_vector_type(8)));
typedef __bf16 bf16x4 __attribute__((ext_vector_type(4)));
typedef float floatx4 __attribute__((ext_vector_type(4)));

#define D_MODEL 4096
#define SEQ 2048
#define BATCH 2
#define NH 32
#define HD 128
#define AL 10
#define MROWS (BATCH * SEQ)   // 4096
#define N_QKV (3 * D_MODEL)   // 12288

static __device__ __forceinline__ void gload_lds16(const void* g, void* l) {
  __builtin_amdgcn_global_load_lds((const __attribute__((address_space(1))) void*)g,
                                   (__attribute__((address_space(3))) void*)l, 16, 0, 0);
}

// max across the 16-lane DPP row via fused v_max + row_ror (VALU latency, no LDS pipe)
#define DPP_MAX_STEP(v, ctrl)                                                             \
  v = fmaxf(v, __int_as_float(__builtin_amdgcn_update_dpp(                                \
                 __float_as_int(v), __float_as_int(v), ctrl, 0xF, 0xF, false)))
static __device__ __forceinline__ float rowmax16(float v) {
  DPP_MAX_STEP(v, 0x128);  // row_ror:8
  DPP_MAX_STEP(v, 0x124);  // row_ror:4
  DPP_MAX_STEP(v, 0x122);  // row_ror:2
  DPP_MAX_STEP(v, 0x121);  // row_ror:1
  return v;
}

// ---------------- fp32 -> bf16 bulk convert ----------------
__global__ void convert_bf16_kernel(const float* __restrict__ src, bf16_t* __restrict__ dst) {
  size_t i = ((size_t)blockIdx.x * 256 + threadIdx.x) * 4;
  float4 v = *(const float4*)(src + i);
  bf16x4 o;
  o[0] = (bf16_t)v.x; o[1] = (bf16_t)v.y; o[2] = (bf16_t)v.z; o[3] = (bf16_t)v.w;
  *(bf16x4*)(dst + i) = o;
}

// ---------------- transpose (D,D) fp32 -> (D,D) bf16 (dst[n][k] = src[k][n]) ----------------
__global__ void transpose_conv_kernel(const float* __restrict__ src, bf16_t* __restrict__ dst) {
  __shared__ float tile[32][33];
  const int tx = threadIdx.x & 31;
  const int ty = threadIdx.x >> 5;
  const int c0 = blockIdx.x * 32;  // source col
  const int r0 = blockIdx.y * 32;  // source row
#pragma unroll
  for (int i = 0; i < 4; i++) {
    int r = ty + i * 8;
    tile[r][tx] = src[(size_t)(r0 + r) * D_MODEL + c0 + tx];
  }
  __syncthreads();
#pragma unroll
  for (int i = 0; i < 4; i++) {
    int r = ty + i * 8;
    dst[(size_t)(c0 + r) * D_MODEL + r0 + tx] = (bf16_t)tile[tx][r];
  }
}

// ---------------- transpose V block of QKV (bf16) -> VT[b][d][s] ----------------
__global__ void vt_kernel(const bf16_t* __restrict__ QKV, bf16_t* __restrict__ VT) {
  __shared__ bf16_t tile[32][33];
  const int tx = threadIdx.x & 31;
  const int ty = threadIdx.x >> 5;
  const int s0 = blockIdx.x * 32;
  const int c0 = blockIdx.y * 32;
  const int b = blockIdx.z;
  const bf16_t* src = QKV + (size_t)b * SEQ * N_QKV + 2 * D_MODEL;
#pragma unroll
  for (int i = 0; i < 4; i++) {
    int r = ty + i * 8;
    tile[r][tx] = src[(size_t)(s0 + r) * N_QKV + c0 + tx];
  }
  __syncthreads();
  bf16_t* dst = VT + (size_t)b * D_MODEL * SEQ;
#pragma unroll
  for (int i = 0; i < 4; i++) {
    int r = ty + i * 8;
    dst[(size_t)(c0 + r) * SEQ + s0 + tx] = tile[tx][r];
  }
}

// ================= 256x256-tile, BK=64, 8-wave, 4-phase/K-tile MFMA GEMM =================
// 8-phase-template port (guide §5): global_load_lds staging with XOR-swizzled source
// (chunk ^= row&7; LDS linear; reads apply the same XOR -> bank-conflict-free ds_read_b128),
// counted vmcnt(8) once per K-tile (tile t+2's 8 loads stay in flight across barriers),
// raw s_barrier + lgkmcnt(0) + sched_barrier(0) (no __syncthreads vmcnt drain),
// setprio(1) around each 16-MFMA cluster, bijective XCD block swizzle (nwg % 8 == 0).
//
// LDS region lifetimes per K-tile (verified): B halves read P1+P2 -> dead after P2;
// A halves read P1+P3 -> dead after P3. Stage (t+2).B at P3, (t+2).A at P4 into buf[t&1].
// vmcnt(8) at P4 completes everything up to tile t+1 (FIFO), leaves t+2's 8 loads in flight.

static __device__ __forceinline__ void stage_half(const bf16_t* src, int ld, int k0,
                                                  bf16_t* dst, int tid) {
  // one 16KB half-tile = 128 rows x 64 bf16; 1024 chunks of 16B; 512 threads x 2 chunks.
  // LDS chunk (row, j) receives global data (row, j ^ (row&7))  [pre-swizzled source]
#pragma unroll
  for (int rr = 0; rr < 2; rr++) {
    const int c = tid + rr * 512;
    const int row = c >> 3;
    const int j = (c & 7) ^ (row & 7);
    gload_lds16(src + (size_t)row * ld + k0 + j * 8, dst + c * 8);
  }
}

static __device__ __forceinline__ bf16x8 read_frag(const bf16_t* half, int row, int chunk) {
  const int j = chunk ^ (row & 7);  // inverse of the staged permutation (XOR involution)
  return *(const bf16x8*)(half + row * 64 + j * 8);
}

#define GSBAR() __builtin_amdgcn_s_barrier()
#define GSCHED0() __builtin_amdgcn_sched_barrier(0)
#define WAIT_LGKM0() asm volatile("s_waitcnt lgkmcnt(0)" ::: "memory")
#define WAIT_VM8() asm volatile("s_waitcnt vmcnt(8)" ::: "memory")
#define WAIT_VM0() asm volatile("s_waitcnt vmcnt(0)" ::: "memory")

template <typename OT>
__global__ __launch_bounds__(512) void gemm256_kernel(const bf16_t* __restrict__ A,
                                                      const bf16_t* __restrict__ Bt,
                                                      OT* __restrict__ C, int M, int N, int K) {
  __shared__ __align__(16) bf16_t sA[2][2][128 * 64];  // [buf][half][row*64+col]
  __shared__ __align__(16) bf16_t sB[2][2][128 * 64];
  const int tid = threadIdx.x;
  const int lane = tid & 63;
  const int wave = tid >> 6;
  const int wm = wave >> 2;   // 0..1  (m half of tile)
  const int wn = wave & 3;    // 0..3  (64-col slice)
  const int quad = lane >> 4;
  const int l16 = lane & 15;
  // bijective XCD swizzle on linear block id (requires nwg % 8 == 0; 768 and 256 both are)
  const int nbx = gridDim.x;
  const int nwg = nbx * gridDim.y;
  const int lin = blockIdx.y * nbx + blockIdx.x;
  const int cpx = nwg >> 3;
  const int swz = (lin & 7) * cpx + (lin >> 3);
  const int m0 = (swz / nbx) * 256;
  const int n0 = (swz % nbx) * 256;
  const int NT = K >> 6;
  const int brow = (wn & 1) * 64;

  floatx4 acc[8][4] = {};

  // ---- prologue: tile0 -> buf0, tile1 -> buf1 (8+8 loads/thread); wait tile0, keep tile1 in flight
  stage_half(A + (size_t)m0 * K, K, 0, sA[0][0], tid);
  stage_half(A + (size_t)(m0 + 128) * K, K, 0, sA[0][1], tid);
  stage_half(Bt + (size_t)n0 * K, K, 0, sB[0][0], tid);
  stage_half(Bt + (size_t)(n0 + 128) * K, K, 0, sB[0][1], tid);
  stage_half(A + (size_t)m0 * K, K, 64, sA[1][0], tid);
  stage_half(A + (size_t)(m0 + 128) * K, K, 64, sA[1][1], tid);
  stage_half(Bt + (size_t)n0 * K, K, 64, sB[1][0], tid);
  stage_half(Bt + (size_t)(n0 + 128) * K, K, 64, sB[1][1], tid);
  WAIT_VM8();
  GSCHED0();
  GSBAR();

  for (int t = 0; t < NT; t++) {
    const int p = t & 1;
    const bf16_t* Ah = sA[p][wm];
    const bf16_t* Bh = sB[p][wn >> 1];
    bf16x8 afr[4][2], bfr[4][2];

    // ---- P1: ds_read A frags 0..3 + B frags 0..1 (12 x ds_read_b128); MFMA m0-3 x n0-1
#pragma unroll
    for (int i = 0; i < 4; i++)
#pragma unroll
      for (int kk = 0; kk < 2; kk++) afr[i][kk] = read_frag(Ah, i * 16 + l16, kk * 4 + quad);
#pragma unroll
    for (int n = 0; n < 2; n++)
#pragma unroll
      for (int kk = 0; kk < 2; kk++)
        bfr[n][kk] = read_frag(Bh, brow + n * 16 + l16, kk * 4 + quad);
    GSBAR();
    WAIT_LGKM0();
    GSCHED0();
    __builtin_amdgcn_s_setprio(1);
#pragma unroll
    for (int i = 0; i < 4; i++)
#pragma unroll
      for (int n = 0; n < 2; n++)
#pragma unroll
        for (int kk = 0; kk < 2; kk++)
          acc[i][n] =
              __builtin_amdgcn_mfma_f32_16x16x32_bf16(afr[i][kk], bfr[n][kk], acc[i][n], 0, 0, 0);
    __builtin_amdgcn_s_setprio(0);
    GSCHED0();
    GSBAR();

    // ---- P2: ds_read B frags 2..3 (4 reads); MFMA m0-3 x n2-3
#pragma unroll
    for (int n = 2; n < 4; n++)
#pragma unroll
      for (int kk = 0; kk < 2; kk++)
        bfr[n][kk] = read_frag(Bh, brow + n * 16 + l16, kk * 4 + quad);
    GSBAR();
    WAIT_LGKM0();
    GSCHED0();
    __builtin_amdgcn_s_setprio(1);
#pragma unroll
    for (int i = 0; i < 4; i++)
#pragma unroll
      for (int n = 2; n < 4; n++)
#pragma unroll
        for (int kk = 0; kk < 2; kk++)
          acc[i][n] =
              __builtin_amdgcn_mfma_f32_16x16x32_bf16(afr[i][kk], bfr[n][kk], acc[i][n], 0, 0, 0);
    __builtin_amdgcn_s_setprio(0);
    GSCHED0();
    GSBAR();

    // ---- P3: ds_read A frags 4..7 (8 reads); stage (t+2).B (B LDS dead after P2); MFMA m4-7 x n0-1
#pragma unroll
    for (int i = 0; i < 4; i++)
#pragma unroll
      for (int kk = 0; kk < 2; kk++)
        afr[i][kk] = read_frag(Ah, (i + 4) * 16 + l16, kk * 4 + quad);
    if (t + 2 < NT) {
      const int k2 = (t + 2) << 6;
      stage_half(Bt + (size_t)n0 * K, K, k2, sB[p][0], tid);
      stage_half(Bt + (size_t)(n0 + 128) * K, K, k2, sB[p][1], tid);
    }
    GSBAR();
    WAIT_LGKM0();
    GSCHED0();
    __builtin_amdgcn_s_setprio(1);
#pragma unroll
    for (int i = 0; i < 4; i++)
#pragma unroll
      for (int n = 0; n < 2; n++)
#pragma unroll
        for (int kk = 0; kk < 2; kk++)
          acc[i + 4][n] = __builtin_amdgcn_mfma_f32_16x16x32_bf16(afr[i][kk], bfr[n][kk],
                                                                  acc[i + 4][n], 0, 0, 0);
    __builtin_amdgcn_s_setprio(0);
    GSCHED0();
    GSBAR();

    // ---- P4: stage (t+2).A (A LDS dead after P3); boundary vmcnt; MFMA m4-7 x n2-3
    if (t + 2 < NT) {
      const int k2 = (t + 2) << 6;
      stage_half(A + (size_t)m0 * K, K, k2, sA[p][0], tid);
      stage_half(A + (size_t)(m0 + 128) * K, K, k2, sA[p][1], tid);
      WAIT_VM8();  // tile t+1 fully landed; t+2's 8 loads remain in flight
    } else if (t + 1 < NT) {
      WAIT_VM0();  // epilogue drain: last tile's stages must land
    }
    GSCHED0();
    GSBAR();
    __builtin_amdgcn_s_setprio(1);
#pragma unroll
    for (int i = 0; i < 4; i++)
#pragma unroll
      for (int n = 2; n < 4; n++)
#pragma unroll
        for (int kk = 0; kk < 2; kk++)
          acc[i + 4][n] = __builtin_amdgcn_mfma_f32_16x16x32_bf16(afr[i][kk], bfr[n][kk],
                                                                  acc[i + 4][n], 0, 0, 0);
    __builtin_amdgcn_s_setprio(0);
    GSCHED0();
    GSBAR();
  }

  // ---- epilogue: C write (C/D layout: col=l16, row=quad*4+r)
#pragma unroll
  for (int i = 0; i < 8; i++)
#pragma unroll
    for (int n = 0; n < 4; n++) {
      const int m = m0 + wm * 128 + i * 16 + quad * 4;
      const int col = n0 + wn * 64 + n * 16 + l16;
#pragma unroll
      for (int r = 0; r < 4; r++) C[(size_t)(m + r) * N + col] = (OT)acc[i][n][r];
    }
}

// ---------------- RoPE in place on Q,K halves of QKV (interleaved pairs) ----------------
__global__ void rope_kernel(bf16_t* __restrict__ QKV, const float* __restrict__ cosb,
                            const float* __restrict__ sinb) {
  int idx = blockIdx.x * 256 + threadIdx.x;  // (row, half, h, i)
  int i = idx & 63;
  int h = (idx >> 6) & 31;
  int half = (idx >> 11) & 1;
  int row = idx >> 12;
  int s = row & (SEQ - 1);
  size_t off = (size_t)row * N_QKV + half * D_MODEL + h * HD + 2 * i;
  float c = cosb[s * 64 + i], sn = sinb[s * 64 + i];
  float x0 = (float)QKV[off], x1 = (float)QKV[off + 1];
  QKV[off] = (bf16_t)(x0 * c - x1 * sn);
  QKV[off + 1] = (bf16_t)(x0 * sn + x1 * c);
}

__global__ void zero_kernel(float* __restrict__ p, int n) {
  int i = blockIdx.x * 256 + threadIdx.x;
  if (i < n) p[i] = 0.f;
}

// ---------------- adapter GEMMs: ak = adapter@wk, av = adapter@wv (fp32) ----------------
__global__ __launch_bounds__(256) void adapter_gemm_kernel(const float* __restrict__ adp,
                                                           const float* __restrict__ wk,
                                                           const float* __restrict__ wv,
                                                           float* __restrict__ ak,
                                                           float* __restrict__ av) {
  const float* W = blockIdx.y ? wv : wk;
  float* out = blockIdx.y ? av : ak;
  const int n = blockIdx.x * 256 + threadIdx.x;
  const int kb = blockIdx.z * 512;
  __shared__ float a_s[AL][512];
  for (int t = threadIdx.x; t < AL * 512; t += 256)
    a_s[t / 512][t % 512] = adp[(t / 512) * D_MODEL + kb + (t % 512)];
  __syncthreads();
  float accv[AL] = {};
  for (int kk = 0; kk < 512; kk++) {
    float w = W[(size_t)(kb + kk) * D_MODEL + n];
#pragma unroll
    for (int a = 0; a < AL; a++) accv[a] += a_s[a][kk] * w;
  }
#pragma unroll
  for (int a = 0; a < AL; a++) atomicAdd(&out[a * D_MODEL + n], accv[a]);
}

// ---------------- flash attention + fused gated adapter attention ----------------
// 4 waves/block; each wave a different head, all sharing one q-tile (uniform loop counts ->
// block barriers valid). Softmax cross-lane work minimized:
//   - row-max: 4 fused DPP row_ror v_max ops (VALU) instead of ds-swizzle shfl chains
//   - row-sum: one mfma(P, ones) per mt -> row-sums land exactly on Ls[mt][r] rows
// Grid = (head-groups, q-tiles reversed): x fastest => longest q-tiles dispatch first (LPT).
// MFMA layouts (HW-verified, guide §3): A: m=lane&15,k=quad*8+j; C/D: col=lane&15,row=quad*4+reg.
__global__ __launch_bounds__(256) void flash_kernel(const bf16_t* __restrict__ QKV,
                                                    const bf16_t* __restrict__ VT,
                                                    const float* __restrict__ akp,
                                                    const float* __restrict__ avp,
                                                    const float* __restrict__ gatep,
                                                    bf16_t* __restrict__ Out) {
  const int lane = threadIdx.x & 63;
  const int wave = threadIdx.x >> 6;
  const int quad = lane >> 4;
  const int l16 = lane & 15;
  const int q0 = (gridDim.y - 1 - blockIdx.y) * 32;  // LPT: longest tiles dispatch first
  const int bh = blockIdx.x * 4 + wave;
  const int b = bh >> 5;
  const int h = bh & 31;
  const size_t base = (size_t)b * SEQ * N_QKV;
  const int hoff = h * HD;
  const float scale = 0.08838834764831845f;  // 1/sqrt(128)
  __shared__ __align__(16) bf16_t Pl[4][2][16][32];

  const bf16_t* vtb = VT + (size_t)(b * D_MODEL + hoff) * SEQ;

  bf16x8 onesf;
#pragma unroll
  for (int j = 0; j < 8; j++) onesf[j] = (bf16_t)1.0f;

  // Q fragments (A-operand), kept in registers for the whole block
  bf16x8 qa[2][4];
#pragma unroll
  for (int mt = 0; mt < 2; mt++) {
    const bf16_t* qrow = QKV + base + (size_t)(q0 + mt * 16 + l16) * N_QKV + hoff + quad * 8;
#pragma unroll
    for (int c = 0; c < 4; c++) qa[mt][c] = *(const bf16x8*)(qrow + c * 32);
  }
  floatx4 acc[2][8] = {};
  float Mx[2][4], Ls[2][4];
#pragma unroll
  for (int mt = 0; mt < 2; mt++)
#pragma unroll
    for (int r = 0; r < 4; r++) { Mx[mt][r] = -1e30f; Ls[mt][r] = 0.f; }

  for (int j0 = 0; j0 <= q0; j0 += 32) {
    // K fragments (B-operand): n=key(lane&15), k=d(quad*8+j) -> contiguous 16B per lane
    bf16x8 kf[2][4];
#pragma unroll
    for (int nt = 0; nt < 2; nt++) {
      const bf16_t* krow =
          QKV + base + (size_t)(j0 + nt * 16 + l16) * N_QKV + D_MODEL + hoff + quad * 8;
#pragma unroll
      for (int c = 0; c < 4; c++) kf[nt][c] = *(const bf16x8*)(krow + c * 32);
    }
    // V fragments from VT[b][d][s]: one contiguous 16B load per dt
    bf16x8 vf[8];
#pragma unroll
    for (int dt = 0; dt < 8; dt++)
      vf[dt] = *(const bf16x8*)(vtb + (size_t)(dt * 16 + l16) * SEQ + j0 + quad * 8);

    const bool diag = (j0 == q0);
#pragma unroll
    for (int mt = 0; mt < 2; mt++) {
      floatx4 s0 = {}, s1 = {};
#pragma unroll
      for (int c = 0; c < 4; c++) {
        s0 = __builtin_amdgcn_mfma_f32_16x16x32_bf16(qa[mt][c], kf[0][c], s0, 0, 0, 0);
        s1 = __builtin_amdgcn_mfma_f32_16x16x32_bf16(qa[mt][c], kf[1][c], s1, 0, 0, 0);
      }
      const int rowg = q0 + mt * 16 + quad * 4;  // + r
#pragma unroll
      for (int r = 0; r < 4; r++) {
        float v0 = s0[r] * scale;
        float v1 = s1[r] * scale;
        if (diag) {
          if (j0 + l16 > rowg + r) v0 = -1e30f;
          if (j0 + 16 + l16 > rowg + r) v1 = -1e30f;
        }
        float mx = rowmax16(fmaxf(v0, v1));  // DPP reduce over the 16-lane row
        float nm = fmaxf(Mx[mt][r], mx);
        float alpha = __expf(Mx[mt][r] - nm);
        Mx[mt][r] = nm;
        float p0 = __expf(v0 - nm);
        float p1 = __expf(v1 - nm);
        Ls[mt][r] *= alpha;  // sum added after P readback via mfma(P, ones)
        Pl[wave][mt][quad * 4 + r][l16] = (bf16_t)p0;
        Pl[wave][mt][quad * 4 + r][l16 + 16] = (bf16_t)p1;
#pragma unroll
        for (int dt = 0; dt < 8; dt++) acc[mt][dt][r] *= alpha;
      }
    }
    __syncthreads();  // P writes -> P reads (C-layout -> A-layout transpose via LDS)
#pragma unroll
    for (int mt = 0; mt < 2; mt++) {
      bf16x8 pf = *(const bf16x8*)(&Pl[wave][mt][l16][quad * 8]);
      floatx4 lz = {};
      lz = __builtin_amdgcn_mfma_f32_16x16x32_bf16(pf, onesf, lz, 0, 0, 0);
#pragma unroll
      for (int dt = 0; dt < 8; dt++)
        acc[mt][dt] = __builtin_amdgcn_mfma_f32_16x16x32_bf16(pf, vf[dt], acc[mt][dt], 0, 0, 0);
#pragma unroll
      for (int r = 0; r < 4; r++) Ls[mt][r] += lz[r];  // row-sum lands on row quad*4+r
    }
    __syncthreads();  // P reads done before next iteration overwrites
  }

  // ---- gated adapter attention (separate softmax over 10 tokens, no mask) ----
  const float gate = gatep[h];
#pragma unroll
  for (int mt = 0; mt < 2; mt++) {
    floatx4 sa = {};
#pragma unroll
    for (int c = 0; c < 4; c++) {
      bf16x8 bak;
#pragma unroll
      for (int jj = 0; jj < 8; jj++) {
        float v = (l16 < AL) ? akp[(size_t)l16 * D_MODEL + hoff + c * 32 + quad * 8 + jj] : 0.f;
        bak[jj] = (bf16_t)v;
      }
      sa = __builtin_amdgcn_mfma_f32_16x16x32_bf16(qa[mt][c], bak, sa, 0, 0, 0);
    }
#pragma unroll
    for (int r = 0; r < 4; r++) {
      float v = (l16 < AL) ? sa[r] * scale : -1e30f;
      float mx = rowmax16(v);
      float p = __expf(v - mx);
      float rs = p;
#pragma unroll
      for (int off = 8; off; off >>= 1) rs += __shfl_xor(rs, off, 64);
      float pa = p / rs;
      Pl[wave][mt][quad * 4 + r][l16] = (l16 < AL) ? (bf16_t)pa : (bf16_t)0.f;
      Pl[wave][mt][quad * 4 + r][l16 + 16] = (bf16_t)0.f;
    }
  }
  __syncthreads();
  bf16x8 avf[8];
#pragma unroll
  for (int jj = 0; jj < 8; jj++) {
    int j = quad * 8 + jj;
#pragma unroll
    for (int dt = 0; dt < 8; dt++) {
      float v = (j < AL) ? avp[(size_t)j * D_MODEL + hoff + dt * 16 + l16] : 0.f;
      avf[dt][jj] = (bf16_t)v;
    }
  }
#pragma unroll
  for (int mt = 0; mt < 2; mt++) {
    bf16x8 pf = *(const bf16x8*)(&Pl[wave][mt][l16][quad * 8]);
#pragma unroll
    for (int dt = 0; dt < 8; dt++) {
      floatx4 z = {};
      floatx4 oa = __builtin_amdgcn_mfma_f32_16x16x32_bf16(pf, avf[dt], z, 0, 0, 0);
#pragma unroll
      for (int r = 0; r < 4; r++) {
        int m = q0 + mt * 16 + quad * 4 + r;
        float val = acc[mt][dt][r] / Ls[mt][r] + gate * oa[r];
        Out[(size_t)(b * SEQ + m) * D_MODEL + hoff + dt * 16 + l16] = (bf16_t)val;
      }
    }
  }
}

extern "C" void kernel_launch(void* const* d_in, const int* in_sizes, int n_in, void* d_out,
                              int out_size, void* d_ws, size_t ws_size, hipStream_t stream) {
  const float* x = (const float*)d_in[0];
  const float* cosb = (const float*)d_in[1];
  const float* sinb = (const float*)d_in[2];
  // d_in[3] = mask (causal, implemented analytically)
  const float* wq = (const float*)d_in[4];
  const float* wk = (const float*)d_in[5];
  const float* wv = (const float*)d_in[6];
  const float* wo = (const float*)d_in[7];
  const float* gate = (const float*)d_in[8];
  const float* adp = (const float*)d_in[9];
  // d_in[10] = random_init (always 0 -> non-concat branch)
  float* out = (float*)d_out;

  char* ws = (char*)d_ws;
  const size_t DD = (size_t)D_MODEL * D_MODEL;
  bf16_t* Wt = (bf16_t*)(ws);                  // (3D, K) stacked wq^T,wk^T,wv^T
  bf16_t* Wot = (bf16_t*)(ws + 3 * DD * 2);    // wo^T
  bf16_t* Xb = (bf16_t*)(ws + 4 * DD * 2);     // x as bf16 (M,K); reused as VT after QKV GEMM
  bf16_t* QKV = (bf16_t*)(ws + 5 * DD * 2);    // (M, 3D)
  bf16_t* Att = (bf16_t*)(ws + 8 * DD * 2);    // (M, D)
  float* akb = (float*)(ws + 9 * DD * 2);      // (AL, D)
  float* avb = akb + AL * D_MODEL;             // (AL, D)
  bf16_t* VT = Xb;                             // (B*D, S) bf16 = DD*2 bytes, Xb dead by then

  convert_bf16_kernel<<<MROWS * D_MODEL / 1024, 256, 0, stream>>>(x, Xb);
  transpose_conv_kernel<<<dim3(128, 128), 256, 0, stream>>>(wq, Wt);
  transpose_conv_kernel<<<dim3(128, 128), 256, 0, stream>>>(wk, Wt + DD);
  transpose_conv_kernel<<<dim3(128, 128), 256, 0, stream>>>(wv, Wt + 2 * DD);
  transpose_conv_kernel<<<dim3(128, 128), 256, 0, stream>>>(wo, Wot);
  gemm256_kernel<bf16_t><<<dim3(N_QKV / 256, MROWS / 256), 512, 0, stream>>>(
      Xb, Wt, QKV, MROWS, N_QKV, D_MODEL);
  rope_kernel<<<(MROWS * 4096) / 256, 256, 0, stream>>>(QKV, cosb, sinb);
  vt_kernel<<<dim3(SEQ / 32, D_MODEL / 32, BATCH), 256, 0, stream>>>(QKV, VT);
  zero_kernel<<<(2 * AL * D_MODEL + 255) / 256, 256, 0, stream>>>(akb, 2 * AL * D_MODEL);
  adapter_gemm_kernel<<<dim3(D_MODEL / 256, 2, 8), 256, 0, stream>>>(adp, wk, wv, akb, avb);
  flash_kernel<<<dim3((BATCH * NH) / 4, SEQ / 32), 256, 0, stream>>>(QKV, VT, akb, avb, gate,
                                                                     Att);
  gemm256_kernel<float><<<dim3(D_MODEL / 256, MROWS / 256), 512, 0, stream>>>(
      Att, Wot, out, MROWS, D_MODEL, D_MODEL);
}